// Round 4
// baseline (178.911 us; speedup 1.0000x reference)
//
#include <hip/hip_runtime.h>
#include <stdint.h>

// Problem constants
#define ROWS  16384   // B*T = 512*32
#define CELL  128
#define INF   512
#define RPB   32      // rows per block
#define NSTEP 32

#define LOG2E 1.4426950408889634f

typedef _Float16 f16x8 __attribute__((ext_vector_type(8)));
typedef _Float16 f16x4 __attribute__((ext_vector_type(4)));
typedef float    f32x16 __attribute__((ext_vector_type(16)));

#define MFMA32(a, b, c) __builtin_amdgcn_mfma_f32_32x32x16_f16((a), (b), (c), 0, 0, 0)

#if __has_builtin(__builtin_amdgcn_exp2f)
#define EXP2(x) __builtin_amdgcn_exp2f(x)
#else
#define EXP2(x) __expf((x) * 0.6931471805599453f)
#endif
#define RCP(x) __builtin_amdgcn_rcpf(x)

// ws layout (f16 elems), all in 32x32x16 A-fragment order (weights are the
// A-operand of the transposed recurrence; A[m=lane&31][k=(lane>>5)*8+j]):
//   cell part: [g<4][w<4][ks<8][lane][j]  at 0        (65536)
//   x    part: [g<4][w<4][ks<32][lane][j] at 65536    (262144)
//   Wc       : [w<4][ks<8][lane][j]       at 327680   (16384)
// Gates f,i1,o prescaled by -log2e (sigmoid), i2 by +2log2e (tanh),
// Wc by +log2e (softmax base-2).
#define XOFF  65536
#define WCOFF 327680
#define WSTOT 344064

__device__ __forceinline__ unsigned short f2h_bits(float f) {
  _Float16 h = (_Float16)f;
  return *(unsigned short*)&h;
}

__global__ __launch_bounds__(256) void prep_kernel(
    const float* __restrict__ Wf, const float* __restrict__ Wi1,
    const float* __restrict__ Wi2, const float* __restrict__ Wo,
    const float* __restrict__ Wc, unsigned short* __restrict__ ws) {
  int id = blockIdx.x * blockDim.x + threadIdx.x;
  if (id >= WSTOT) return;
  const float* Wg[4] = {Wf, Wi1, Wi2, Wo};
  const float sc[4] = {-LOG2E, -LOG2E, 2.f * LOG2E, -LOG2E};
  if (id < XOFF) {                       // cell part: W^T[m=n][k] = W[k][n]
    int g = id >> 14, r = id & 16383;
    int w = r >> 12, ks = (r >> 9) & 7, lane = (r >> 3) & 63, j = r & 7;
    int k = ks * 16 + ((lane >> 5) << 3) + j;
    int n = w * 32 + (lane & 31);
    ws[id] = f2h_bits(Wg[g][k * CELL + n] * sc[g]);
  } else if (id < WCOFF) {               // x part (W rows 128..639)
    int t = id - XOFF;
    int g = t >> 16, r = t & 65535;
    int w = r >> 14, ks = (r >> 9) & 31, lane = (r >> 3) & 63, j = r & 7;
    int k = ks * 16 + ((lane >> 5) << 3) + j;
    int n = w * 32 + (lane & 31);
    ws[id] = f2h_bits(Wg[g][(CELL + k) * CELL + n] * sc[g]);
  } else {                               // Wc, scaled +log2e
    int r = id - WCOFF;
    int w = r >> 12, ks = (r >> 9) & 7, lane = (r >> 3) & 63, j = r & 7;
    int k = ks * 16 + ((lane >> 5) << 3) + j;
    int n = w * 32 + (lane & 31);
    ws[id] = f2h_bits(Wc[k * CELL + n] * LOG2E);
  }
}

// Transposed recurrence: z^T = W^T (A, in VGPRs) x c^T (B, LDS).
// D layout: col(lane&31) = batch row, row(reg-map) = cell col.
// 2 blocks/CU, 43008 B LDS.
__global__ __launch_bounds__(256, 2) void lstm_kernel(
    const float* __restrict__ x,
    const float* __restrict__ bf_, const float* __restrict__ bi1,
    const float* __restrict__ bi2, const float* __restrict__ bo,
    const float* __restrict__ bc,
    const unsigned short* __restrict__ ws, float* __restrict__ out) {

  __shared__ union {
    _Float16 xs[32][264];                    // 16896 B, x^T staging [row][xcol]
    struct {
      _Float16 o[32][136];                   // 8704 B,  o^T [row][ocol]
      float    s[32][132];                   // 16896 B, s^T [row][scol]
    } ep;                                    // 25600 B
  } uS;
  __shared__ _Float16 cT[2][32][136];        // 17408 B, c [batch-row][cell-col]

  const int tid  = threadIdx.x;
  const int lane = tid & 63;
  const int w    = tid >> 6;     // wave w owns cell-cols [w*32, w*32+32)
  const int n31  = lane & 31;    // this lane's batch row
  const int l5   = lane >> 5;
  const int r0   = blockIdx.x * RPB;

  const _Float16* Aw  = (const _Float16*)ws;
  const _Float16* Xw  = (const _Float16*)ws + XOFF;
  const _Float16* Wcw = (const _Float16*)ws + WCOFF;

  // ---------------- precompute u^T = Wx^T @ x^T (2 chunks of 256) ---------
  f32x16 u[4];
#pragma unroll
  for (int g = 0; g < 4; ++g)
#pragma unroll
    for (int i = 0; i < 16; ++i) u[g][i] = 0.f;

  const float* xbase = x + (size_t)r0 * INF;
#pragma unroll 1
  for (int ch = 0; ch < 2; ++ch) {
    if (ch) __syncthreads();
#pragma unroll
    for (int i = 0; i < 8; ++i) {
      int flat = tid + i * 256;            // 2048 = 32 rows * 64 float4
      int row = flat >> 6, c4 = flat & 63;
      const float4 v = ((const float4*)(xbase + (size_t)row * INF + ch * 256))[c4];
      f16x4 h = {(_Float16)v.x, (_Float16)v.y, (_Float16)v.z, (_Float16)v.w};
      *(f16x4*)&uS.xs[row][c4 * 4] = h;
    }
    __syncthreads();
#pragma unroll 2
    for (int ksl = 0; ksl < 16; ++ksl) {
      f16x8 b = *(const f16x8*)&uS.xs[n31][ksl * 16 + l5 * 8];
      int ks = ch * 16 + ksl;
#pragma unroll
      for (int g = 0; g < 4; ++g) {
        f16x8 a = *(const f16x8*)(Xw + (((g * 4 + w) * 32 + ks) * 64 + lane) * 8);
        u[g] = MFMA32(a, b, u[g]);
      }
    }
  }
  // prescaled biases
#pragma unroll
  for (int reg = 0; reg < 16; ++reg) {
    int col = w * 32 + (reg & 3) + 8 * (reg >> 2) + 4 * l5;
    u[0][reg] += bf_[col] * (-LOG2E);
    u[1][reg] += bi1[col] * (-LOG2E);
    u[2][reg] += bi2[col] * (2.f * LOG2E);
    u[3][reg] += bo[col]  * (-LOG2E);
  }

  // ---------------- recurrent-gate weights (A-frags) -> 96 VGPRs ----------
  f16x8 wr[3][8];
#pragma unroll
  for (int g = 0; g < 3; ++g)
#pragma unroll
    for (int ks = 0; ks < 8; ++ks)
      wr[g][ks] = *(const f16x8*)(Aw + (((g * 4 + w) * 8 + ks) * 64 + lane) * 8);

  // ---------------- step 0: c_prev = 0 => z = u ---------------------------
  f32x16 cr;
#pragma unroll
  for (int reg = 0; reg < 16; ++reg) {
    float ig = RCP(1.f + EXP2(u[1][reg]));
    float gg = fmaf(-2.f, RCP(1.f + EXP2(u[2][reg])), 1.f);
    cr[reg] = ig * gg;
  }
#pragma unroll
  for (int qd = 0; qd < 4; ++qd) {
    f16x4 p = {(_Float16)cr[qd * 4 + 0], (_Float16)cr[qd * 4 + 1],
               (_Float16)cr[qd * 4 + 2], (_Float16)cr[qd * 4 + 3]};
    *(f16x4*)&cT[0][n31][w * 32 + qd * 8 + l5 * 4] = p;
  }
  __syncthreads();

  // ---------------- recurrence: steps 1..30 -------------------------------
#pragma unroll 1
  for (int t = 1; t < NSTEP - 1; ++t) {
    const int rb = (t + 1) & 1, wb = t & 1;
    f16x8 b[8];
#pragma unroll
    for (int ks = 0; ks < 8; ++ks)
      b[ks] = *(const f16x8*)&cT[rb][n31][ks * 16 + l5 * 8];
    f32x16 zf = u[0], zi1 = u[1], zi2 = u[2];
#pragma unroll
    for (int ks = 0; ks < 8; ++ks) {
      zf  = MFMA32(wr[0][ks], b[ks], zf);
      zi1 = MFMA32(wr[1][ks], b[ks], zi1);
      zi2 = MFMA32(wr[2][ks], b[ks], zi2);
    }
#pragma unroll
    for (int reg = 0; reg < 16; ++reg) {
      float fg = RCP(1.f + EXP2(zf[reg]));
      float ig = RCP(1.f + EXP2(zi1[reg]));
      float gg = fmaf(-2.f, RCP(1.f + EXP2(zi2[reg])), 1.f);
      cr[reg] = fmaf(cr[reg], fg, ig * gg);
    }
#pragma unroll
    for (int qd = 0; qd < 4; ++qd) {
      f16x4 p = {(_Float16)cr[qd * 4 + 0], (_Float16)cr[qd * 4 + 1],
                 (_Float16)cr[qd * 4 + 2], (_Float16)cr[qd * 4 + 3]};
      *(f16x4*)&cT[wb][n31][w * 32 + qd * 8 + l5 * 4] = p;
    }
    __syncthreads();
  }

  // ---------------- final step (t=31): + o-gate ---------------------------
  {
    f16x8 b[8];
#pragma unroll
    for (int ks = 0; ks < 8; ++ks)
      b[ks] = *(const f16x8*)&cT[0][n31][ks * 16 + l5 * 8];
    f32x16 zf = u[0], zi1 = u[1], zi2 = u[2], zo = u[3];
#pragma unroll
    for (int ks = 0; ks < 8; ++ks) {
      f16x8 wof = *(const f16x8*)(Aw + (((3 * 4 + w) * 8 + ks) * 64 + lane) * 8);
      zf  = MFMA32(wr[0][ks], b[ks], zf);
      zi1 = MFMA32(wr[1][ks], b[ks], zi1);
      zi2 = MFMA32(wr[2][ks], b[ks], zi2);
      zo  = MFMA32(wof, b[ks], zo);
    }
    float ovv[16];
#pragma unroll
    for (int reg = 0; reg < 16; ++reg) {
      float fg = RCP(1.f + EXP2(zf[reg]));
      float ig = RCP(1.f + EXP2(zi1[reg]));
      float gg = fmaf(-2.f, RCP(1.f + EXP2(zi2[reg])), 1.f);
      float cn = fmaf(cr[reg], fg, ig * gg);
      cr[reg] = cn;
      float th = fmaf(-2.f, RCP(1.f + EXP2(cn * (2.f * LOG2E))), 1.f);
      ovv[reg] = RCP(1.f + EXP2(zo[reg])) * th;
    }
#pragma unroll
    for (int qd = 0; qd < 4; ++qd) {
      f16x4 p = {(_Float16)ovv[qd * 4 + 0], (_Float16)ovv[qd * 4 + 1],
                 (_Float16)ovv[qd * 4 + 2], (_Float16)ovv[qd * 4 + 3]};
      *(f16x4*)&uS.ep.o[n31][w * 32 + qd * 8 + l5 * 4] = p;
    }
    __syncthreads();
  }

  // ---------------- epilogue: s^T = Wc^T @ o^T, softmax -------------------
  {
    f32x16 sa;
#pragma unroll
    for (int i = 0; i < 16; ++i) sa[i] = 0.f;
#pragma unroll
    for (int ks = 0; ks < 8; ++ks) {
      f16x8 a = *(const f16x8*)(Wcw + ((w * 8 + ks) * 64 + lane) * 8);
      f16x8 b = *(const f16x8*)&uS.ep.o[n31][ks * 16 + l5 * 8];
      sa = MFMA32(a, b, sa);
    }
#pragma unroll
    for (int reg = 0; reg < 16; ++reg) {
      int col = w * 32 + (reg & 3) + 8 * (reg >> 2) + 4 * l5;
      sa[reg] += bc[col] * LOG2E;
    }
#pragma unroll
    for (int qd = 0; qd < 4; ++qd) {
      float4 p = {sa[qd * 4 + 0], sa[qd * 4 + 1], sa[qd * 4 + 2], sa[qd * 4 + 3]};
      *(float4*)&uS.ep.s[n31][w * 32 + qd * 8 + l5 * 4] = p;
    }
    __syncthreads();

    // wave w reduces rows w*8 .. w*8+7; s is scaled by log2e -> base-2 softmax
#pragma unroll
    for (int rr = 0; rr < 8; ++rr) {
      int r = w * 8 + rr;
      float v0 = uS.ep.s[r][lane];
      float v1 = uS.ep.s[r][lane + 64];
      float m = fmaxf(v0, v1);
#pragma unroll
      for (int off = 32; off; off >>= 1) m = fmaxf(m, __shfl_xor(m, off, 64));
      float e0 = EXP2(v0 - m), e1 = EXP2(v1 - m);
      float sm = e0 + e1;
#pragma unroll
      for (int off = 32; off; off >>= 1) sm += __shfl_xor(sm, off, 64);
      float inv = RCP(sm);
      size_t base = (size_t)(r0 + r) * 128;
      out[base + lane]      = e0 * inv;
      out[base + lane + 64] = e1 * inv;
    }

    // final c (output 1): lane owns batch row n31, quads of cell cols
#pragma unroll
    for (int qd = 0; qd < 4; ++qd) {
      float4 p = {cr[qd * 4 + 0], cr[qd * 4 + 1], cr[qd * 4 + 2], cr[qd * 4 + 3]};
      *(float4*)&out[(size_t)ROWS * 128 + (size_t)(r0 + n31) * 128 +
                     w * 32 + qd * 8 + l5 * 4] = p;
    }
  }
}

extern "C" void kernel_launch(void* const* d_in, const int* in_sizes, int n_in,
                              void* d_out, int out_size, void* d_ws, size_t ws_size,
                              hipStream_t stream) {
  const float* x   = (const float*)d_in[0];
  const float* Wf  = (const float*)d_in[1];
  const float* bf_ = (const float*)d_in[2];
  const float* Wi1 = (const float*)d_in[3];
  const float* bi1 = (const float*)d_in[4];
  const float* Wi2 = (const float*)d_in[5];
  const float* bi2 = (const float*)d_in[6];
  const float* Wo  = (const float*)d_in[7];
  const float* bo  = (const float*)d_in[8];
  const float* Wc  = (const float*)d_in[9];
  const float* bc  = (const float*)d_in[10];
  unsigned short* ws = (unsigned short*)d_ws;
  float* out = (float*)d_out;

  hipLaunchKernelGGL(prep_kernel, dim3((WSTOT + 255) / 256), dim3(256), 0, stream,
                     Wf, Wi1, Wi2, Wo, Wc, ws);
  hipLaunchKernelGGL(lstm_kernel, dim3(ROWS / RPB), dim3(256), 0, stream,
                     x, bf_, bi1, bi2, bo, bc, ws, out);
}